// Round 11
// baseline (134.332 us; speedup 1.0000x reference)
//
#include <hip/hip_runtime.h>
#include <stdint.h>

#define NROWS 8192
#define HALF_N 4096
#define DIM 512          /* elements per row; == bytes per row in fp8 */
#define INV_TEMP 2.0f
#define E2SCALE 2.8853900817779268f  /* INV_TEMP * log2(e) */
#define LN2 0.6931471805599453f
#define NTILES 2080

typedef int i32x8 __attribute__((ext_vector_type(8)));
typedef float f32x16 __attribute__((ext_vector_type(16)));

// One wave per row: sumsq -> rsqrt -> fp8 e4m3 store (4 MB). Zeroes sumexp.
__global__ void __launch_bounds__(256) k_normalize(const float* __restrict__ zi,
                                                   const float* __restrict__ zj,
                                                   unsigned char* __restrict__ zn,
                                                   float* __restrict__ sumexp) {
  int tid = threadIdx.x;
  int gid = blockIdx.x * 256 + tid;
  if (gid < NROWS) sumexp[gid] = 0.0f;
  int wave = tid >> 6, lane = tid & 63;
  int row = blockIdx.x * 4 + wave;
  const float* src = (row < HALF_N) ? (zi + (size_t)row * DIM)
                                    : (zj + (size_t)(row - HALF_N) * DIM);
  const float4* s4 = (const float4*)src;
  float4 a = s4[lane];        // cols 4*lane .. +3
  float4 b = s4[lane + 64];   // cols 256+4*lane .. +3
  float ss = a.x * a.x + a.y * a.y + a.z * a.z + a.w * a.w +
             b.x * b.x + b.y * b.y + b.z * b.z + b.w * b.w;
#pragma unroll
  for (int off = 32; off > 0; off >>= 1) ss += __shfl_xor(ss, off, 64);
  float inv = 1.0f / fmaxf(sqrtf(ss), 1e-8f);
  int w0 = __builtin_amdgcn_cvt_pk_fp8_f32(a.x * inv, a.y * inv, 0, false);
  w0 = __builtin_amdgcn_cvt_pk_fp8_f32(a.z * inv, a.w * inv, w0, true);
  int w1 = __builtin_amdgcn_cvt_pk_fp8_f32(b.x * inv, b.y * inv, 0, false);
  w1 = __builtin_amdgcn_cvt_pk_fp8_f32(b.z * inv, b.w * inv, w1, true);
  unsigned char* dst = zn + (size_t)row * DIM;
  *((int*)(dst + lane * 4)) = w0;
  *((int*)(dst + 256 + lane * 4)) = w1;
}

// Upper-triangular 128x128 tiles (sim symmetric): off-diag tiles feed row- AND col-sums.
// LDS-FREE K-loop: zn is 4 MB and L2-resident, and the 32x32x64 fp8 A/B fragment layout
// (lane c32 holds row's bytes h*32..h*32+31) is directly loadable with two b128 global
// loads per fragment. Removes the LDS critical pipe (~3000 cyc/tile), all K-loop
// barriers, and all bank conflicts; the compiler batches the fully-unrolled loads with
// fine-grained vmcnt. Fused-finalize reverted (R8-R10: last-block serialized tail cost
// more than the k_final launch it saved). No per-block device fences (R5: wbl2 storm).
__global__ void __launch_bounds__(256) k_simsum(const unsigned char* __restrict__ zn,
                                                float* __restrict__ sumexp,
                                                float* __restrict__ posv) {
  int tid = threadIdx.x;
  int wave = tid >> 6, lane = tid & 63;

  // triangular decode, tn-major: idx = tn(tn+1)/2 + tm, tm <= tn
  int idx = blockIdx.x;
  int tn = (int)((sqrtf(8.0f * idx + 1.0f) - 1.0f) * 0.5f);
  while (tn * (tn + 1) / 2 > idx) tn--;
  while ((tn + 1) * (tn + 2) / 2 <= idx) tn++;
  int tm = idx - tn * (tn + 1) / 2;
  int rowBase = tm * 128, colBase = tn * 128;
  int wr = (wave >> 1) * 64, wc = (wave & 1) * 64;  // wave's 64x64 quadrant
  int h = lane >> 5, c32 = lane & 31;               // k-half and row/col within 32-block

  // Direct fragment base pointers: lane (c32,h) reads row's bytes h*32 .. h*32+31.
  // Window s adds byte offset s*64 (emitted as an immediate; max 448+16 fits 13-bit).
  const unsigned char* A0 = zn + (size_t)(rowBase + wr + c32) * DIM + h * 32;
  const unsigned char* A1 = A0 + 32 * DIM;
  const unsigned char* B0 = zn + (size_t)(colBase + wc + c32) * DIM + h * 32;
  const unsigned char* B1 = B0 + 32 * DIM;

  f32x16 acc[2][2];
#pragma unroll
  for (int i = 0; i < 2; i++)
#pragma unroll
    for (int j = 0; j < 2; j++)
#pragma unroll
      for (int r = 0; r < 16; r++) acc[i][j][r] = 0.f;

#define LD8(p, off)                                                        \
  ({                                                                       \
    int4 lo = *(const int4*)((p) + (off));                                 \
    int4 hi = *(const int4*)((p) + (off) + 16);                            \
    (i32x8){lo.x, lo.y, lo.z, lo.w, hi.x, hi.y, hi.z, hi.w};               \
  })

#pragma unroll
  for (int s = 0; s < 8; s++) {
    int o = s * 64;
    i32x8 a0 = LD8(A0, o);
    i32x8 a1 = LD8(A1, o);
    i32x8 b0 = LD8(B0, o);
    i32x8 b1 = LD8(B1, o);
    acc[0][0] = __builtin_amdgcn_mfma_scale_f32_32x32x64_f8f6f4(a0, b0, acc[0][0],
                                                                0, 0, 0, 0x7F, 0, 0x7F);
    acc[0][1] = __builtin_amdgcn_mfma_scale_f32_32x32x64_f8f6f4(a0, b1, acc[0][1],
                                                                0, 0, 0, 0x7F, 0, 0x7F);
    acc[1][0] = __builtin_amdgcn_mfma_scale_f32_32x32x64_f8f6f4(a1, b0, acc[1][0],
                                                                0, 0, 0, 0x7F, 0, 0x7F);
    acc[1][1] = __builtin_amdgcn_mfma_scale_f32_32x32x64_f8f6f4(a1, b1, acc[1][1],
                                                                0, 0, 0, 0x7F, 0, 0x7F);
  }
#undef LD8

  // ---- Epilogue. 32x32 C/D layout: col = lane&31, row = (reg&3)+8*(reg>>2)+4*h. ----
  bool isDiag = (tm == tn);
  bool hasPos = (tn == tm + 32);
  bool diagLane = (wr == wc) && (h == ((c32 >> 2) & 1));  // lane holding row==col elems
  int rsel = (c32 & 3) | ((c32 >> 3) << 2);               // reg with rowIn32 == c32

  if (isDiag && diagLane) {
    acc[0][0][rsel] = -1e30f;  // exp2 -> 0 (mask diagonal)
    acc[1][1][rsel] = -1e30f;
  }
  if (hasPos && diagLane) {
#pragma unroll
    for (int i = 0; i < 2; i++) {
      float sv = acc[i][i][rsel] * INV_TEMP;
      int gr = rowBase + wr + i * 32 + c32;
      posv[gr] = sv;            // unique (row,col) across grid -> race-free plain store
      posv[gr + HALF_N] = sv;   // sim symmetric
    }
  }

  float rp[32], cp[2] = {0.f, 0.f};
#pragma unroll
  for (int i = 0; i < 2; i++)
#pragma unroll
    for (int r = 0; r < 16; r++) {
      float e0 = __builtin_amdgcn_exp2f(acc[i][0][r] * E2SCALE);
      float e1 = __builtin_amdgcn_exp2f(acc[i][1][r] * E2SCALE);
      rp[i * 16 + r] = e0 + e1;
      cp[0] += e0;
      cp[1] += e1;
    }

  // Fold-reduce rp[32] across the 32-lane half; lane ends with v = c32.
#pragma unroll
  for (int t = 0; t < 16; t++) {
    float mine = (lane & 16) ? rp[t + 16] : rp[t];
    float oth = __shfl_xor((lane & 16) ? rp[t] : rp[t + 16], 16, 64);
    rp[t] = mine + oth;
  }
#pragma unroll
  for (int t = 0; t < 8; t++) {
    float mine = (lane & 8) ? rp[t + 8] : rp[t];
    float oth = __shfl_xor((lane & 8) ? rp[t] : rp[t + 8], 8, 64);
    rp[t] = mine + oth;
  }
#pragma unroll
  for (int t = 0; t < 4; t++) {
    float mine = (lane & 4) ? rp[t + 4] : rp[t];
    float oth = __shfl_xor((lane & 4) ? rp[t] : rp[t + 4], 4, 64);
    rp[t] = mine + oth;
  }
#pragma unroll
  for (int t = 0; t < 2; t++) {
    float mine = (lane & 2) ? rp[t + 2] : rp[t];
    float oth = __shfl_xor((lane & 2) ? rp[t] : rp[t + 2], 2, 64);
    rp[t] = mine + oth;
  }
  {
    float mine = (lane & 1) ? rp[1] : rp[0];
    float oth = __shfl_xor((lane & 1) ? rp[0] : rp[1], 1, 64);
    rp[0] = mine + oth;
  }
  int myrow = rowBase + wr + 32 * (c32 >> 4) + (c32 & 3) + 8 * ((c32 >> 2) & 3) + 4 * h;
  atomicAdd(&sumexp[myrow], rp[0]);

  if (!isDiag) {
    // col sums: sum the two k-halves' contributions, then lane h picks col-block j=h
    cp[0] += __shfl_xor(cp[0], 32, 64);
    cp[1] += __shfl_xor(cp[1], 32, 64);
    float cv = h ? cp[1] : cp[0];
    atomicAdd(&sumexp[colBase + wc + h * 32 + c32], cv);
  }
}

__global__ void __launch_bounds__(1024) k_final(const float* __restrict__ sumexp,
                                                const float* __restrict__ posv,
                                                float* __restrict__ out) {
  __shared__ float red[16];
  int tid = threadIdx.x;
  const float4* se4 = (const float4*)sumexp;
  const float4* pv4 = (const float4*)posv;
  float p = 0.f;
#pragma unroll
  for (int c = 0; c < 2; c++) {
    float4 se = se4[tid * 2 + c];
    float4 pv = pv4[tid * 2 + c];
    p += (__builtin_amdgcn_logf(se.x) + __builtin_amdgcn_logf(se.y) +
          __builtin_amdgcn_logf(se.z) + __builtin_amdgcn_logf(se.w)) * LN2 -
         (pv.x + pv.y + pv.z + pv.w);
  }
#pragma unroll
  for (int off = 32; off > 0; off >>= 1) p += __shfl_xor(p, off, 64);
  int wv = tid >> 6, ln = tid & 63;
  if (ln == 0) red[wv] = p;
  __syncthreads();
  if (tid == 0) {
    float t = 0.f;
    for (int w = 0; w < 16; w++) t += red[w];
    out[0] = t / (float)NROWS;
  }
}

extern "C" void kernel_launch(void* const* d_in, const int* in_sizes, int n_in,
                              void* d_out, int out_size, void* d_ws, size_t ws_size,
                              hipStream_t stream) {
  const float* zi = (const float*)d_in[0];
  const float* zj = (const float*)d_in[1];
  unsigned char* zn = (unsigned char*)d_ws;                           // 4 MB fp8
  float* sumexp = (float*)((char*)d_ws + (size_t)NROWS * DIM);        // 32 KB
  float* posv = sumexp + NROWS;                                       // 32 KB
  float* out = (float*)d_out;

  hipLaunchKernelGGL(k_normalize, dim3(2048), dim3(256), 0, stream, zi, zj, zn, sumexp);
  hipLaunchKernelGGL(k_simsum, dim3(NTILES), dim3(256), 0, stream, zn, sumexp, posv);
  hipLaunchKernelGGL(k_final, dim3(1), dim3(1024), 0, stream, sumexp, posv, out);
}

// Round 12
// 98.472 us; speedup vs baseline: 1.3642x; 1.3642x over previous
//
#include <hip/hip_runtime.h>
#include <stdint.h>

#define NROWS 8192
#define HALF_N 4096
#define DIM 512          /* elements per row; == bytes per row in fp8 */
#define INV_TEMP 2.0f
#define E2SCALE 2.8853900817779268f  /* INV_TEMP * log2(e) */
#define LN2 0.6931471805599453f
#define NTILES 2080
#define PANEL_BYTES 16384  /* 32 rows x 512 B, stored [s][q][h][c32][16] */

typedef int i32x8 __attribute__((ext_vector_type(8)));
typedef float f32x16 __attribute__((ext_vector_type(16)));

// One block per 32-row panel: normalize rows (one wave per row, 8 rows/wave),
// fp8-convert into LDS, then write the panel in MFMA-fragment order:
//   packed[p][s][q][h][c32][b] = row (32p+c32), byte k = s*64 + h*32 + q*16 + b
// With this layout a k_simsum fragment load is panelBase + s*2048 + q*1024 + lane*16
// -> perfectly coalesced (fixes R11's 512-B-strided request storm).
__global__ void __launch_bounds__(256) k_normalize(const float* __restrict__ zi,
                                                   const float* __restrict__ zj,
                                                   unsigned char* __restrict__ zn,
                                                   float* __restrict__ sumexp) {
  __shared__ __align__(16) unsigned char buf[32 * 512];  // 16 KB
  int tid = threadIdx.x;
  int wave = tid >> 6, lane = tid & 63;
  int panel = blockIdx.x;
  if (panel < 32) sumexp[panel * 256 + tid] = 0.0f;  // zero 8192 floats across 32 blocks

#pragma unroll
  for (int i = 0; i < 8; i++) {
    int rloc = wave * 8 + i;
    int row = panel * 32 + rloc;
    const float* src = (row < HALF_N) ? (zi + (size_t)row * DIM)
                                      : (zj + (size_t)(row - HALF_N) * DIM);
    const float4* s4 = (const float4*)src;
    float4 a = s4[lane];        // cols 4*lane .. +3
    float4 b = s4[lane + 64];   // cols 256+4*lane .. +3
    float ss = a.x * a.x + a.y * a.y + a.z * a.z + a.w * a.w +
               b.x * b.x + b.y * b.y + b.z * b.z + b.w * b.w;
#pragma unroll
    for (int off = 32; off > 0; off >>= 1) ss += __shfl_xor(ss, off, 64);
    float inv = 1.0f / fmaxf(sqrtf(ss), 1e-8f);
    int w0 = __builtin_amdgcn_cvt_pk_fp8_f32(a.x * inv, a.y * inv, 0, false);
    w0 = __builtin_amdgcn_cvt_pk_fp8_f32(a.z * inv, a.w * inv, w0, true);
    int w1 = __builtin_amdgcn_cvt_pk_fp8_f32(b.x * inv, b.y * inv, 0, false);
    w1 = __builtin_amdgcn_cvt_pk_fp8_f32(b.z * inv, b.w * inv, w1, true);
    *((int*)(buf + rloc * 512 + lane * 4)) = w0;
    *((int*)(buf + rloc * 512 + 256 + lane * 4)) = w1;
  }
  __syncthreads();

  unsigned char* pb = zn + (size_t)panel * PANEL_BYTES;
#pragma unroll
  for (int it = 0; it < 4; it++) {
    int o = (it * 256 + tid) * 16;         // packed byte offset, 16-B granule
    int s = o >> 11;
    int rem = o & 2047;
    int q = (rem >> 10) & 1;
    int h = (rem >> 9) & 1;
    int c32 = (rem >> 4) & 31;
    int k = s * 64 + h * 32 + q * 16;      // source byte within row
    int4 v = *((const int4*)(buf + c32 * 512 + k));
    *((int4*)(pb + o)) = v;                // coalesced: lane-contiguous granules
  }
}

// Upper-triangular 128x128 tiles (sim symmetric): off-diag tiles feed row- AND col-sums.
// LDS-FREE K-loop on the packed-fragment zn layout: every fragment load is a fully
// coalesced 1-KB global_load_dwordx4 from L2 (4 MB zn, read-only, cached per-XCD).
// No barriers, no LDS, no bank conflicts in the K-loop; latency hidden by the 8-deep
// unroll + 4 blocks/CU of wave-level TLP. (R11's uncoalesced variant was request-bound;
// R7's LDS variant paid 16 barrier drains + 2.1M conflict cycles per dispatch.)
__global__ void __launch_bounds__(256) k_simsum(const unsigned char* __restrict__ zn,
                                                float* __restrict__ sumexp,
                                                float* __restrict__ posv) {
  int tid = threadIdx.x;
  int wave = tid >> 6, lane = tid & 63;

  // triangular decode, tn-major: idx = tn(tn+1)/2 + tm, tm <= tn
  int idx = blockIdx.x;
  int tn = (int)((sqrtf(8.0f * idx + 1.0f) - 1.0f) * 0.5f);
  while (tn * (tn + 1) / 2 > idx) tn--;
  while ((tn + 1) * (tn + 2) / 2 <= idx) tn++;
  int tm = idx - tn * (tn + 1) / 2;
  int rowBase = tm * 128, colBase = tn * 128;
  int wr = (wave >> 1) * 64, wc = (wave & 1) * 64;  // wave's 64x64 quadrant
  int h = lane >> 5, c32 = lane & 31;               // k-half and row/col within 32-block

  // Packed panel bases for this wave's fragments (panel = 32 rows).
  const unsigned char* pA0 = zn + (size_t)(tm * 4 + (wave >> 1) * 2) * PANEL_BYTES + lane * 16;
  const unsigned char* pA1 = pA0 + PANEL_BYTES;
  const unsigned char* pB0 = zn + (size_t)(tn * 4 + (wave & 1) * 2) * PANEL_BYTES + lane * 16;
  const unsigned char* pB1 = pB0 + PANEL_BYTES;

  f32x16 acc[2][2];
#pragma unroll
  for (int i = 0; i < 2; i++)
#pragma unroll
    for (int j = 0; j < 2; j++)
#pragma unroll
      for (int r = 0; r < 16; r++) acc[i][j][r] = 0.f;

#define LD8(p, s)                                                          \
  ({                                                                       \
    int4 lo = *(const int4*)((p) + (s) * 2048);                            \
    int4 hi = *(const int4*)((p) + (s) * 2048 + 1024);                     \
    (i32x8){lo.x, lo.y, lo.z, lo.w, hi.x, hi.y, hi.z, hi.w};               \
  })

#pragma unroll
  for (int s = 0; s < 8; s++) {
    i32x8 a0 = LD8(pA0, s);
    i32x8 a1 = LD8(pA1, s);
    i32x8 b0 = LD8(pB0, s);
    i32x8 b1 = LD8(pB1, s);
    acc[0][0] = __builtin_amdgcn_mfma_scale_f32_32x32x64_f8f6f4(a0, b0, acc[0][0],
                                                                0, 0, 0, 0x7F, 0, 0x7F);
    acc[0][1] = __builtin_amdgcn_mfma_scale_f32_32x32x64_f8f6f4(a0, b1, acc[0][1],
                                                                0, 0, 0, 0x7F, 0, 0x7F);
    acc[1][0] = __builtin_amdgcn_mfma_scale_f32_32x32x64_f8f6f4(a1, b0, acc[1][0],
                                                                0, 0, 0, 0x7F, 0, 0x7F);
    acc[1][1] = __builtin_amdgcn_mfma_scale_f32_32x32x64_f8f6f4(a1, b1, acc[1][1],
                                                                0, 0, 0, 0x7F, 0, 0x7F);
  }
#undef LD8

  // ---- Epilogue. 32x32 C/D layout: col = lane&31, row = (reg&3)+8*(reg>>2)+4*h. ----
  bool isDiag = (tm == tn);
  bool hasPos = (tn == tm + 32);
  bool diagLane = (wr == wc) && (h == ((c32 >> 2) & 1));  // lane holding row==col elems
  int rsel = (c32 & 3) | ((c32 >> 3) << 2);               // reg with rowIn32 == c32

  if (isDiag && diagLane) {
    acc[0][0][rsel] = -1e30f;  // exp2 -> 0 (mask diagonal)
    acc[1][1][rsel] = -1e30f;
  }
  if (hasPos && diagLane) {
#pragma unroll
    for (int i = 0; i < 2; i++) {
      float sv = acc[i][i][rsel] * INV_TEMP;
      int gr = rowBase + wr + i * 32 + c32;
      posv[gr] = sv;            // unique (row,col) across grid -> race-free plain store
      posv[gr + HALF_N] = sv;   // sim symmetric
    }
  }

  float rp[32], cp[2] = {0.f, 0.f};
#pragma unroll
  for (int i = 0; i < 2; i++)
#pragma unroll
    for (int r = 0; r < 16; r++) {
      float e0 = __builtin_amdgcn_exp2f(acc[i][0][r] * E2SCALE);
      float e1 = __builtin_amdgcn_exp2f(acc[i][1][r] * E2SCALE);
      rp[i * 16 + r] = e0 + e1;
      cp[0] += e0;
      cp[1] += e1;
    }

  // Fold-reduce rp[32] across the 32-lane half; lane ends with v = c32.
#pragma unroll
  for (int t = 0; t < 16; t++) {
    float mine = (lane & 16) ? rp[t + 16] : rp[t];
    float oth = __shfl_xor((lane & 16) ? rp[t] : rp[t + 16], 16, 64);
    rp[t] = mine + oth;
  }
#pragma unroll
  for (int t = 0; t < 8; t++) {
    float mine = (lane & 8) ? rp[t + 8] : rp[t];
    float oth = __shfl_xor((lane & 8) ? rp[t] : rp[t + 8], 8, 64);
    rp[t] = mine + oth;
  }
#pragma unroll
  for (int t = 0; t < 4; t++) {
    float mine = (lane & 4) ? rp[t + 4] : rp[t];
    float oth = __shfl_xor((lane & 4) ? rp[t] : rp[t + 4], 4, 64);
    rp[t] = mine + oth;
  }
#pragma unroll
  for (int t = 0; t < 2; t++) {
    float mine = (lane & 2) ? rp[t + 2] : rp[t];
    float oth = __shfl_xor((lane & 2) ? rp[t] : rp[t + 2], 2, 64);
    rp[t] = mine + oth;
  }
  {
    float mine = (lane & 1) ? rp[1] : rp[0];
    float oth = __shfl_xor((lane & 1) ? rp[0] : rp[1], 1, 64);
    rp[0] = mine + oth;
  }
  int myrow = rowBase + wr + 32 * (c32 >> 4) + (c32 & 3) + 8 * ((c32 >> 2) & 3) + 4 * h;
  atomicAdd(&sumexp[myrow], rp[0]);

  if (!isDiag) {
    // col sums: sum the two k-halves' contributions, then lane h picks col-block j=h
    cp[0] += __shfl_xor(cp[0], 32, 64);
    cp[1] += __shfl_xor(cp[1], 32, 64);
    float cv = h ? cp[1] : cp[0];
    atomicAdd(&sumexp[colBase + wc + h * 32 + c32], cv);
  }
}

__global__ void __launch_bounds__(1024) k_final(const float* __restrict__ sumexp,
                                                const float* __restrict__ posv,
                                                float* __restrict__ out) {
  __shared__ float red[16];
  int tid = threadIdx.x;
  const float4* se4 = (const float4*)sumexp;
  const float4* pv4 = (const float4*)posv;
  float p = 0.f;
#pragma unroll
  for (int c = 0; c < 2; c++) {
    float4 se = se4[tid * 2 + c];
    float4 pv = pv4[tid * 2 + c];
    p += (__builtin_amdgcn_logf(se.x) + __builtin_amdgcn_logf(se.y) +
          __builtin_amdgcn_logf(se.z) + __builtin_amdgcn_logf(se.w)) * LN2 -
         (pv.x + pv.y + pv.z + pv.w);
  }
#pragma unroll
  for (int off = 32; off > 0; off >>= 1) p += __shfl_xor(p, off, 64);
  int wv = tid >> 6, ln = tid & 63;
  if (ln == 0) red[wv] = p;
  __syncthreads();
  if (tid == 0) {
    float t = 0.f;
    for (int w = 0; w < 16; w++) t += red[w];
    out[0] = t / (float)NROWS;
  }
}

extern "C" void kernel_launch(void* const* d_in, const int* in_sizes, int n_in,
                              void* d_out, int out_size, void* d_ws, size_t ws_size,
                              hipStream_t stream) {
  const float* zi = (const float*)d_in[0];
  const float* zj = (const float*)d_in[1];
  unsigned char* zn = (unsigned char*)d_ws;                           // 4 MB fp8, packed
  float* sumexp = (float*)((char*)d_ws + (size_t)NROWS * DIM);        // 32 KB
  float* posv = sumexp + NROWS;                                       // 32 KB
  float* out = (float*)d_out;

  hipLaunchKernelGGL(k_normalize, dim3(256), dim3(256), 0, stream, zi, zj, zn, sumexp);
  hipLaunchKernelGGL(k_simsum, dim3(NTILES), dim3(256), 0, stream, zn, sumexp, posv);
  hipLaunchKernelGGL(k_final, dim3(1), dim3(1024), 0, stream, sumexp, posv, out);
}

// Round 13
// 97.121 us; speedup vs baseline: 1.3831x; 1.0139x over previous
//
#include <hip/hip_runtime.h>
#include <stdint.h>

#define NROWS 8192
#define HALF_N 4096
#define DIM 512          /* elements per row; == bytes per row in fp8 */
#define SQRT_E2 1.6986436f  /* sqrt(2*log2(e)); zn scaled by this so acc = E2SCALE*cos */
#define LN2 0.6931471805599453f
#define NTILES 2080
#define PANEL_BYTES 16384  /* 32 rows x 512 B, stored [s][q][h][c32][16] */

typedef int i32x8 __attribute__((ext_vector_type(8)));
typedef float f32x16 __attribute__((ext_vector_type(16)));

// One wave per row, LDS-free: normalize, scale by sqrt(E2SCALE), fp8-convert, and
// scatter-store DIRECTLY into the packed fragment layout (each 16-B granule holds one
// row's bytes, so no cross-row staging is needed: granule of col c lives at
// (c>>6)*2048 + ((c>>4)&1)*1024 + ((c>>5)&1)*512 + (row&31)*16 + (c&15)).
__global__ void __launch_bounds__(256) k_normalize(const float* __restrict__ zi,
                                                   const float* __restrict__ zj,
                                                   unsigned char* __restrict__ zn,
                                                   float* __restrict__ sumexp) {
  int tid = threadIdx.x;
  int gid = blockIdx.x * 256 + tid;
  if (gid < NROWS) sumexp[gid] = 0.0f;
  int wave = tid >> 6, lane = tid & 63;
  int row = blockIdx.x * 4 + wave;
  const float* src = (row < HALF_N) ? (zi + (size_t)row * DIM)
                                    : (zj + (size_t)(row - HALF_N) * DIM);
  const float4* s4 = (const float4*)src;
  float4 a = s4[lane];        // cols 4*lane .. +3
  float4 b = s4[lane + 64];   // cols 256+4*lane .. +3
  float ss = a.x * a.x + a.y * a.y + a.z * a.z + a.w * a.w +
             b.x * b.x + b.y * b.y + b.z * b.z + b.w * b.w;
#pragma unroll
  for (int off = 32; off > 0; off >>= 1) ss += __shfl_xor(ss, off, 64);
  float inv = SQRT_E2 / fmaxf(sqrtf(ss), 1e-8f);
  int w0 = __builtin_amdgcn_cvt_pk_fp8_f32(a.x * inv, a.y * inv, 0, false);
  w0 = __builtin_amdgcn_cvt_pk_fp8_f32(a.z * inv, a.w * inv, w0, true);
  int w1 = __builtin_amdgcn_cvt_pk_fp8_f32(b.x * inv, b.y * inv, 0, false);
  w1 = __builtin_amdgcn_cvt_pk_fp8_f32(b.z * inv, b.w * inv, w1, true);
  // packed offsets: w0 covers col c=4*lane (s=lane>>4); w1 covers c=256+4*lane (s+4)
  unsigned char* pb = zn + (size_t)(row >> 5) * PANEL_BYTES;
  int o0 = (lane >> 4) * 2048 + ((lane >> 2) & 1) * 1024 + ((lane >> 3) & 1) * 512 +
           (row & 31) * 16 + ((4 * lane) & 15);
  *((int*)(pb + o0)) = w0;
  *((int*)(pb + o0 + 8192)) = w1;
}

// Upper-triangular 128x128 tiles (sim symmetric): off-diag tiles feed row- AND col-sums.
// LDS-free K-loop on the packed-fragment zn: every fragment load is a fully coalesced
// 1-KB global_load_dwordx4 from L2. acc = E2SCALE*cos (temperature folded into zn's
// scale), so the epilogue is exp2(acc) with no per-element multiply; pos = acc*LN2.
__global__ void __launch_bounds__(256) k_simsum(const unsigned char* __restrict__ zn,
                                                float* __restrict__ sumexp,
                                                float* __restrict__ posv) {
  int tid = threadIdx.x;
  int wave = tid >> 6, lane = tid & 63;

  // triangular decode, tn-major: idx = tn(tn+1)/2 + tm, tm <= tn
  int idx = blockIdx.x;
  int tn = (int)((sqrtf(8.0f * idx + 1.0f) - 1.0f) * 0.5f);
  while (tn * (tn + 1) / 2 > idx) tn--;
  while ((tn + 1) * (tn + 2) / 2 <= idx) tn++;
  int tm = idx - tn * (tn + 1) / 2;
  int rowBase = tm * 128, colBase = tn * 128;
  int wr = (wave >> 1) * 64, wc = (wave & 1) * 64;  // wave's 64x64 quadrant
  int h = lane >> 5, c32 = lane & 31;               // k-half and row/col within 32-block

  // Packed panel bases for this wave's fragments (panel = 32 rows).
  const unsigned char* pA0 = zn + (size_t)(tm * 4 + (wave >> 1) * 2) * PANEL_BYTES + lane * 16;
  const unsigned char* pA1 = pA0 + PANEL_BYTES;
  const unsigned char* pB0 = zn + (size_t)(tn * 4 + (wave & 1) * 2) * PANEL_BYTES + lane * 16;
  const unsigned char* pB1 = pB0 + PANEL_BYTES;

  f32x16 acc[2][2];
#pragma unroll
  for (int i = 0; i < 2; i++)
#pragma unroll
    for (int j = 0; j < 2; j++)
#pragma unroll
      for (int r = 0; r < 16; r++) acc[i][j][r] = 0.f;

#define LD8(p, s)                                                          \
  ({                                                                       \
    int4 lo = *(const int4*)((p) + (s) * 2048);                            \
    int4 hi = *(const int4*)((p) + (s) * 2048 + 1024);                     \
    (i32x8){lo.x, lo.y, lo.z, lo.w, hi.x, hi.y, hi.z, hi.w};               \
  })

#pragma unroll
  for (int s = 0; s < 8; s++) {
    i32x8 a0 = LD8(pA0, s);
    i32x8 a1 = LD8(pA1, s);
    i32x8 b0 = LD8(pB0, s);
    i32x8 b1 = LD8(pB1, s);
    acc[0][0] = __builtin_amdgcn_mfma_scale_f32_32x32x64_f8f6f4(a0, b0, acc[0][0],
                                                                0, 0, 0, 0x7F, 0, 0x7F);
    acc[0][1] = __builtin_amdgcn_mfma_scale_f32_32x32x64_f8f6f4(a0, b1, acc[0][1],
                                                                0, 0, 0, 0x7F, 0, 0x7F);
    acc[1][0] = __builtin_amdgcn_mfma_scale_f32_32x32x64_f8f6f4(a1, b0, acc[1][0],
                                                                0, 0, 0, 0x7F, 0, 0x7F);
    acc[1][1] = __builtin_amdgcn_mfma_scale_f32_32x32x64_f8f6f4(a1, b1, acc[1][1],
                                                                0, 0, 0, 0x7F, 0, 0x7F);
  }
#undef LD8

  // ---- Epilogue. 32x32 C/D layout: col = lane&31, row = (reg&3)+8*(reg>>2)+4*h. ----
  bool isDiag = (tm == tn);
  bool hasPos = (tn == tm + 32);
  bool diagLane = (wr == wc) && (h == ((c32 >> 2) & 1));  // lane holding row==col elems
  int rsel = (c32 & 3) | ((c32 >> 3) << 2);               // reg with rowIn32 == c32

  if (isDiag && diagLane) {
    acc[0][0][rsel] = -1e30f;  // exp2 -> 0 (mask diagonal)
    acc[1][1][rsel] = -1e30f;
  }
  if (hasPos && diagLane) {
#pragma unroll
    for (int i = 0; i < 2; i++) {
      float sv = acc[i][i][rsel] * LN2;  // acc = E2SCALE*cos -> *ln2 = cos/TEMP
      int gr = rowBase + wr + i * 32 + c32;
      posv[gr] = sv;            // unique (row,col) across grid -> race-free plain store
      posv[gr + HALF_N] = sv;   // sim symmetric
    }
  }

  float rp[32], cp[2] = {0.f, 0.f};
#pragma unroll
  for (int i = 0; i < 2; i++)
#pragma unroll
    for (int r = 0; r < 16; r++) {
      float e0 = __builtin_amdgcn_exp2f(acc[i][0][r]);
      float e1 = __builtin_amdgcn_exp2f(acc[i][1][r]);
      rp[i * 16 + r] = e0 + e1;
      cp[0] += e0;
      cp[1] += e1;
    }

  // Fold-reduce rp[32] across the 32-lane half; lane ends with v = c32.
#pragma unroll
  for (int t = 0; t < 16; t++) {
    float mine = (lane & 16) ? rp[t + 16] : rp[t];
    float oth = __shfl_xor((lane & 16) ? rp[t] : rp[t + 16], 16, 64);
    rp[t] = mine + oth;
  }
#pragma unroll
  for (int t = 0; t < 8; t++) {
    float mine = (lane & 8) ? rp[t + 8] : rp[t];
    float oth = __shfl_xor((lane & 8) ? rp[t] : rp[t + 8], 8, 64);
    rp[t] = mine + oth;
  }
#pragma unroll
  for (int t = 0; t < 4; t++) {
    float mine = (lane & 4) ? rp[t + 4] : rp[t];
    float oth = __shfl_xor((lane & 4) ? rp[t] : rp[t + 4], 4, 64);
    rp[t] = mine + oth;
  }
#pragma unroll
  for (int t = 0; t < 2; t++) {
    float mine = (lane & 2) ? rp[t + 2] : rp[t];
    float oth = __shfl_xor((lane & 2) ? rp[t] : rp[t + 2], 2, 64);
    rp[t] = mine + oth;
  }
  {
    float mine = (lane & 1) ? rp[1] : rp[0];
    float oth = __shfl_xor((lane & 1) ? rp[0] : rp[1], 1, 64);
    rp[0] = mine + oth;
  }
  int myrow = rowBase + wr + 32 * (c32 >> 4) + (c32 & 3) + 8 * ((c32 >> 2) & 3) + 4 * h;
  atomicAdd(&sumexp[myrow], rp[0]);

  if (!isDiag) {
    // col sums: sum the two k-halves' contributions, then lane h picks col-block j=h
    cp[0] += __shfl_xor(cp[0], 32, 64);
    cp[1] += __shfl_xor(cp[1], 32, 64);
    float cv = h ? cp[1] : cp[0];
    atomicAdd(&sumexp[colBase + wc + h * 32 + c32], cv);
  }
}

__global__ void __launch_bounds__(1024) k_final(const float* __restrict__ sumexp,
                                                const float* __restrict__ posv,
                                                float* __restrict__ out) {
  __shared__ float red[16];
  int tid = threadIdx.x;
  const float4* se4 = (const float4*)sumexp;
  const float4* pv4 = (const float4*)posv;
  float p = 0.f;
#pragma unroll
  for (int c = 0; c < 2; c++) {
    float4 se = se4[tid * 2 + c];
    float4 pv = pv4[tid * 2 + c];
    p += (__builtin_amdgcn_logf(se.x) + __builtin_amdgcn_logf(se.y) +
          __builtin_amdgcn_logf(se.z) + __builtin_amdgcn_logf(se.w)) * LN2 -
         (pv.x + pv.y + pv.z + pv.w);
  }
#pragma unroll
  for (int off = 32; off > 0; off >>= 1) p += __shfl_xor(p, off, 64);
  int wv = tid >> 6, ln = tid & 63;
  if (ln == 0) red[wv] = p;
  __syncthreads();
  if (tid == 0) {
    float t = 0.f;
    for (int w = 0; w < 16; w++) t += red[w];
    out[0] = t / (float)NROWS;
  }
}

extern "C" void kernel_launch(void* const* d_in, const int* in_sizes, int n_in,
                              void* d_out, int out_size, void* d_ws, size_t ws_size,
                              hipStream_t stream) {
  const float* zi = (const float*)d_in[0];
  const float* zj = (const float*)d_in[1];
  unsigned char* zn = (unsigned char*)d_ws;                           // 4 MB fp8, packed
  float* sumexp = (float*)((char*)d_ws + (size_t)NROWS * DIM);        // 32 KB
  float* posv = sumexp + NROWS;                                       // 32 KB
  float* out = (float*)d_out;

  hipLaunchKernelGGL(k_normalize, dim3(2048), dim3(256), 0, stream, zi, zj, zn, sumexp);
  hipLaunchKernelGGL(k_simsum, dim3(NTILES), dim3(256), 0, stream, zn, sumexp, posv);
  hipLaunchKernelGGL(k_final, dim3(1), dim3(1024), 0, stream, sumexp, posv, out);
}